// Round 10
// baseline (1149.815 us; speedup 1.0000x reference)
//
#include <hip/hip_runtime.h>

// OmniMambaBlock — round 10: k_gin tile trim + dt-in-dtcum, k_chunk global-CUM
// (no LDS conflicts), xn+gates fusion, fuse+mean fusion, k_scan re-grid.

typedef unsigned short u16;
typedef unsigned int   u32;
typedef __attribute__((ext_vector_type(8))) short short8;      // bf16x8
typedef __attribute__((ext_vector_type(8))) _Float16 half8;    // fp16x8
typedef __attribute__((ext_vector_type(4))) float f32x4;

#define LSEQ 32768
#define CDIM 128
#define NPROJ 644
#define CCH 384
#define DIN 256
#define NHD 4
#define CKL 128
#define NCHK 256

__device__ __forceinline__ float b2f(u16 u){ u32 x=((u32)u)<<16; float f; __builtin_memcpy(&f,&x,4); return f; }
__device__ __forceinline__ u16 f2b(float f){ u32 x; __builtin_memcpy(&x,&f,4); x += 0x7fffu + ((x>>16)&1u); return (u16)(x>>16); }
__device__ __forceinline__ u16 f2h(float v){ _Float16 h=(_Float16)v; u16 b; __builtin_memcpy(&b,&h,2); return b; }
__device__ __forceinline__ float h2f(u16 b){ _Float16 h; __builtin_memcpy(&h,&b,2); return (float)h; }
__device__ __forceinline__ void up4(uint2 v, float* o){
  union { uint2 u; _Float16 h[4]; } c; c.u = v;
  o[0]=(float)c.h[0]; o[1]=(float)c.h[1]; o[2]=(float)c.h[2]; o[3]=(float)c.h[3];
}
__device__ __forceinline__ uint2 pk4(const float* o){
  union { uint2 u; _Float16 h[4]; } c;
  c.h[0]=(_Float16)o[0]; c.h[1]=(_Float16)o[1]; c.h[2]=(_Float16)o[2]; c.h[3]=(_Float16)o[3];
  return c.u;
}
__device__ __forceinline__ float sigmoidf_(float v){ return 1.f/(1.f+__expf(-v)); }
__device__ __forceinline__ float siluf_(float v){ return v*sigmoidf_(v); }
__device__ __forceinline__ float softplusf_(float v){ return (v>20.f)? v : log1pf(__expf(v)); }

__device__ __forceinline__ int seq2sp(int t, int run){
  int te = (run&1) ? (LSEQ-1-t) : t;
  int a = te>>10, b=(te>>5)&31, c=te&31;
  int d,h,w;
  switch(run>>1){
    case 0: d=a; h=b; w=c; break;
    case 1: h=a; d=b; w=c; break;
    default: w=a; d=b; h=c; break;
  }
  return (d<<10)|(h<<5)|w;
}

// ---------------- K1: fused rmsnorm + gate softmax --------------------------
__global__ void k_xng(const float* __restrict__ x, const float* __restrict__ nw,
                      const float* __restrict__ gw, const float* __restrict__ gb,
                      float* __restrict__ XN, float* __restrict__ G){
  int s = blockIdx.x*256 + threadIdx.x;
  float ss = 0.f;
  #pragma unroll 8
  for (int c=0;c<CDIM;c++){ float v=x[c*LSEQ+s]; ss += v*v; }
  float sc = rsqrtf(ss*(1.f/CDIM)+1e-6f);
  float a[6];
  #pragma unroll
  for (int j=0;j<6;j++) a[j]=gb[j];
  #pragma unroll 4
  for (int c=0;c<CDIM;c++){
    float xnv = x[c*LSEQ+s]*sc*nw[c];
    XN[c*LSEQ+s] = xnv;
    #pragma unroll
    for (int j=0;j<6;j++) a[j] += xnv*gw[c*6+j];
  }
  float m=a[0];
  #pragma unroll
  for (int j=1;j<6;j++) m = fmaxf(m,a[j]);
  float e[6], ssum=0.f;
  #pragma unroll
  for (int j=0;j<6;j++){ e[j]=__expf(a[j]-m); ssum+=e[j]; }
  float inv = 1.f/ssum;
  #pragma unroll
  for (int j=0;j<6;j++) G[j*LSEQ+s] = e[j]*inv;
}

// ---------------- K_perm: XNT[t][c] bf16, sequence-ordered ------------------
__global__ __launch_bounds__(256) void k_permute(const float* __restrict__ XN, u16* __restrict__ XNT, int dir){
  __shared__ u16 TS[128*34];
  int a = blockIdx.x>>5, b = blockIdx.x&31;
  int tid = threadIdx.x;
  int spa = (dir==1)? b : a;
  int spb = (dir==1)? a : b;
  int spbase = spa*1024 + spb*32;
  for (int idx=tid; idx<4096; idx+=256){
    int c = idx>>5, i = idx&31;
    TS[c*34+i] = f2b(XN[c*LSEQ + spbase + i]);
  }
  __syncthreads();
  for (int idx=tid; idx<4096; idx+=256){
    int i = idx>>7, c = idx&127;
    int t = (dir==2) ? (i*1024 + a*32 + b) : (a*1024 + b*32 + i);
    XNT[t*128 + c] = TS[c*34+i];
  }
}

// ---------------- K_prepw: WinT[j][k] bf16, j<640 ---------------------------
__global__ void k_prepw(const float* __restrict__ Win, u16* __restrict__ WinT){
  int idx = blockIdx.x*256 + threadIdx.x;   // 640*128 = 81920
  int j = idx>>7, k = idx&127;
  WinT[idx] = f2b(Win[k*NPROJ + j]);
}

// ---------------- K_prewo: WoT[c][k] fp16 (Wout transposed) -----------------
__global__ void k_prewo(const float* __restrict__ Wout, u16* __restrict__ WoT){
  int idx = blockIdx.x*256 + threadIdx.x;
  int c = idx>>8, k = idx&255;
  WoT[idx] = f2h(Wout[k*CDIM + c]);
}

// ---------------- K2: ZX[t,j<640] = XNT[t,:]·WinT[j,:]  (bf16 MFMA) ---------
__global__ __launch_bounds__(256) void k_gin_mfma(const u16* __restrict__ XNT, const u16* __restrict__ WinT,
                                                  u16* __restrict__ ZX, int flip){
  __shared__ u16 Asb[128*136];
  __shared__ u16 Bsb[128*136];
  int j0 = blockIdx.x*128, t0 = blockIdx.y*128;
  int tid = threadIdx.x;
  for (int ch = tid; ch < 2048; ch += 256){
    int row = ch>>4, c8 = ch&15;
    int tg = flip ? (LSEQ-1-(t0+row)) : (t0+row);
    uint4 av = *(const uint4*)(XNT + tg*128 + c8*8);
    *(uint4*)(&Asb[row*136 + c8*8]) = av;
    uint4 bv = *(const uint4*)(WinT + (j0+row)*128 + c8*8);
    *(uint4*)(&Bsb[row*136 + c8*8]) = bv;
  }
  __syncthreads();
  int lane = tid&63, wid = tid>>6;
  int wm = (wid>>1)*64, wn = (wid&1)*64;
  int lm = lane&15, lq = lane>>4;
  f32x4 acc[4][4] = {};
  for (int kt=0; kt<4; kt++){
    short8 af[4], bf[4];
    #pragma unroll
    for (int mt=0;mt<4;mt++) af[mt] = *(const short8*)(&Asb[(wm+mt*16+lm)*136 + kt*32 + lq*8]);
    #pragma unroll
    for (int nt=0;nt<4;nt++) bf[nt] = *(const short8*)(&Bsb[(wn+nt*16+lm)*136 + kt*32 + lq*8]);
    #pragma unroll
    for (int mt=0;mt<4;mt++)
      #pragma unroll
      for (int nt=0;nt<4;nt++)
        acc[mt][nt] = __builtin_amdgcn_mfma_f32_16x16x32_bf16(af[mt], bf[nt], acc[mt][nt], 0,0,0);
  }
  #pragma unroll
  for (int mt=0;mt<4;mt++){
    #pragma unroll
    for (int nt=0;nt<4;nt++){
      int j = j0 + wn + nt*16 + lm;
      #pragma unroll
      for (int r=0;r<4;r++){
        int t = t0 + wm + mt*16 + lq*4 + r;
        ZX[t*NPROJ + j] = f2h(acc[mt][nt][r]);
      }
    }
  }
}

// ---------------- K3a: causal depthwise conv1d K=4 + silu -> XB fp16 --------
__global__ __launch_bounds__(384) void k_conv(const u16* __restrict__ ZX, const float* __restrict__ cw,
                                              const float* __restrict__ cb, u16* __restrict__ XB){
  __shared__ u16 smc[35*384];
  int t0 = blockIdx.x*32;
  int tid = threadIdx.x;
  for (int idx=tid; idx<13440; idx+=384){
    int j = idx/384, chh = idx - j*384;
    int t = t0-3+j;
    smc[idx] = (t>=0)? ZX[t*NPROJ + 256 + chh] : (u16)0;
  }
  __syncthreads();
  int ch = tid;
  float w0=cw[ch*4], w1=cw[ch*4+1], w2=cw[ch*4+2], w3=cw[ch*4+3], bb=cb[ch];
  for (int i=0;i<32;i++){
    float acc = w0*h2f(smc[i*384+ch]) + w1*h2f(smc[(i+1)*384+ch])
              + w2*h2f(smc[(i+2)*384+ch]) + w3*h2f(smc[(i+3)*384+ch]) + bb;
    XB[(t0+i)*CCH + ch] = f2h(siluf_(acc));
  }
}

// ---------------- K3b: dt = softplus(XNT·Win_dt + b) + chunk cumsum ---------
__global__ __launch_bounds__(256) void k_dtcum(const u16* __restrict__ XNT, const float* __restrict__ Win,
                                               const float* __restrict__ dtb, const float* __restrict__ Alog,
                                               float* __restrict__ DT, float* __restrict__ CUM,
                                               float* __restrict__ CDEC, int flip){
  int g = blockIdx.x*4 + (threadIdx.x>>6);
  int lane = threadIdx.x&63;
  int c = g>>2, h = g&3;
  float A = -__expf(Alog[h]);
  float bias = dtb[h];
  int t0 = c*CKL + lane*2;
  int tg0 = flip ? (LSEQ-1-t0) : t0;
  int tg1 = flip ? (LSEQ-1-(t0+1)) : (t0+1);
  const u16* row0 = XNT + tg0*128;
  const u16* row1 = XNT + tg1*128;
  float r0 = 0.f, r1 = 0.f;
  for (int k8=0; k8<16; k8++){
    uint4 a0 = *(const uint4*)(row0 + k8*8);
    uint4 a1 = *(const uint4*)(row1 + k8*8);
    const u16* p0 = (const u16*)&a0;
    const u16* p1 = (const u16*)&a1;
    #pragma unroll
    for (int j=0;j<8;j++){
      float wv = Win[(k8*8+j)*NPROJ + 640 + h];
      r0 += b2f(p0[j])*wv;
      r1 += b2f(p1[j])*wv;
    }
  }
  float d0 = softplusf_(r0+bias), d1 = softplusf_(r1+bias);
  DT[t0*4+h] = d0; DT[(t0+1)*4+h] = d1;
  float e0 = d0*A, e1 = d1*A;
  float s = e0+e1;
  #pragma unroll
  for (int off=1; off<64; off<<=1){
    float v = __shfl_up(s, off, 64);
    if (lane>=off) s += v;
  }
  CUM[t0*4+h] = s - e1;
  CUM[(t0+1)*4+h] = s;
  float tot = __shfl(s, 63, 64);
  if (lane==0) CDEC[c*4+h] = __expf(tot);
}

// ---------------- K4: per (chunk,head) — CUM from global (no LDS conflicts) -
__global__ __launch_bounds__(256) void k_chunk(const u16* __restrict__ XB, const float* __restrict__ DT,
                                               const float* __restrict__ CUM, const float* __restrict__ Dp,
                                               u16* __restrict__ YA, u16* __restrict__ ST){
  __shared__ u16 sh[27136];
  u16* Cs   = sh;           // [128][72]
  u16* Bsm  = sh + 9216;    // [128][72]
  u16* BdeT = sh;           // [64][136] overlays Cs after CB
  u16* Mh   = sh;           // [128][136] overlays Cs+Bsm after S
  u16* Xsh  = sh + 18432;   // [64][136]

  int bid = blockIdx.x; int c = bid>>2, h = bid&3;
  int tid = threadIdx.x, lane = tid&63, wid = tid>>6;
  int lm = lane&15, lq = lane>>4;
  const float* CUMc = CUM + (c*CKL)*4 + h;

  for (int idx=tid; idx<1024; idx+=256){
    int t = idx>>3, b8 = idx&7;
    const u16* row = XB + (c*CKL+t)*CCH;
    *(uint4*)&Cs[t*72 + b8*8]  = *(const uint4*)(row + 320 + b8*8);
    *(uint4*)&Bsm[t*72 + b8*8] = *(const uint4*)(row + 256 + b8*8);
  }
  for (int idx=tid; idx<8192; idx+=256){
    int t = idx>>6, n = idx&63;
    float xv = h2f(XB[(c*CKL+t)*CCH + h*64 + n]) * DT[(c*CKL+t)*4 + h];
    Xsh[n*136 + t] = f2h(xv);
  }
  // per-lane cum_t for the M phase (registers, global L2-hot)
  float cum_t[2][4];
  #pragma unroll
  for (int mt=0;mt<2;mt++)
    #pragma unroll
    for (int r=0;r<4;r++) cum_t[mt][r] = CUMc[(wid*32+mt*16+lq*4+r)*4];
  float cl = CUMc[127*4];
  __syncthreads();

  // ---- CB = C·B^T (triangular tiles only) ----
  f32x4 cbac[2][8] = {};
  for (int kt=0; kt<2; kt++){
    half8 af0 = *(const half8*)&Cs[(wid*32+ 0+lm)*72 + kt*32 + lq*8];
    half8 af1 = *(const half8*)&Cs[(wid*32+16+lm)*72 + kt*32 + lq*8];
    #pragma unroll
    for (int nt=0;nt<8;nt++){
      if (nt <= wid*2+1){
        half8 bfv = *(const half8*)&Bsm[(nt*16+lm)*72 + kt*32 + lq*8];
        if (nt <= wid*2)
          cbac[0][nt] = __builtin_amdgcn_mfma_f32_16x16x32_f16(af0, bfv, cbac[0][nt], 0,0,0);
        cbac[1][nt] = __builtin_amdgcn_mfma_f32_16x16x32_f16(af1, bfv, cbac[1][nt], 0,0,0);
      }
    }
  }
  __syncthreads();   // CB reads of Cs done -> overwrite with BdeT

  // ---- BdeT[n][s] = B[s][n]*exp(cum_last - cum_s) ----
  for (int idx=tid; idx<8192; idx+=256){
    int s = idx&127, n = idx>>7;
    float de = __expf(cl - CUMc[s*4]);
    BdeT[n*136+s] = f2h(h2f(Bsm[s*72+n]) * de);
  }
  __syncthreads();

  // ---- S = xdt^T @ BdeT^T ----
  f32x4 sa[4] = {};
  for (int kt=0; kt<4; kt++){
    half8 aa = *(const half8*)&Xsh[(wid*16+lm)*136 + kt*32 + lq*8];
    #pragma unroll
    for (int nt=0;nt<4;nt++){
      half8 bfv = *(const half8*)&BdeT[(nt*16+lm)*136 + kt*32 + lq*8];
      sa[nt] = __builtin_amdgcn_mfma_f32_16x16x32_f16(aa, bfv, sa[nt], 0,0,0);
    }
  }
  #pragma unroll
  for (int nt=0;nt<4;nt++){
    int n = nt*16 + lm;
    #pragma unroll
    for (int r=0;r<4;r++){
      int p = wid*16 + lq*4 + r;
      ST[((c*4+h)*64 + p)*64 + n] = f2h(sa[nt][r]);
    }
  }
  __syncthreads();   // S reads of BdeT done -> overwrite with Mh

  // ---- M build (wave-private rows; only tiles this wave's Y_intra reads) ---
  #pragma unroll
  for (int mt=0;mt<2;mt++){
    int tb = wid*32 + mt*16;
    int diag = wid*2 + mt;
    int hi = wid*2 + 1;
    #pragma unroll
    for (int nt=0;nt<8;nt++){
      if (nt > hi) break;
      int s = nt*16 + lm;
      if (nt > diag){
        #pragma unroll
        for (int r=0;r<4;r++) Mh[(tb+lq*4+r)*136+s] = 0;
      } else {
        float cums = CUMc[s*4];
        if (nt == diag){
          #pragma unroll
          for (int r=0;r<4;r++){
            int t = tb + lq*4 + r;
            float m = (s<=t)? cbac[mt][nt][r]*__expf(cum_t[mt][r]-cums) : 0.f;
            Mh[t*136+s] = f2h(m);
          }
        } else {
          #pragma unroll
          for (int r=0;r<4;r++){
            int t = tb + lq*4 + r;
            Mh[t*136+s] = f2h(cbac[mt][nt][r]*__expf(cum_t[mt][r]-cums));
          }
        }
      }
    }
  }
  // no barrier: M rows are written and read by the same wave

  // ---- Y_intra = M @ xdt (K-tiles up to diagonal) + D*xh epilogue ----
  f32x4 ya[2][4] = {};
  for (int kt=0; kt<=wid; kt++){
    half8 af[2], bfv[4];
    #pragma unroll
    for (int mt=0;mt<2;mt++) af[mt] = *(const half8*)&Mh[(wid*32+mt*16+lm)*136 + kt*32 + lq*8];
    #pragma unroll
    for (int nt=0;nt<4;nt++) bfv[nt] = *(const half8*)&Xsh[(nt*16+lm)*136 + kt*32 + lq*8];
    #pragma unroll
    for (int mt=0;mt<2;mt++)
      #pragma unroll
      for (int nt=0;nt<4;nt++)
        ya[mt][nt] = __builtin_amdgcn_mfma_f32_16x16x32_f16(af[mt], bfv[nt], ya[mt][nt], 0,0,0);
  }
  float dval = Dp[h];
  #pragma unroll
  for (int mt=0;mt<2;mt++){
    #pragma unroll
    for (int nt=0;nt<4;nt++){
      int p = nt*16 + lm;
      #pragma unroll
      for (int r=0;r<4;r++){
        int t = wid*32 + mt*16 + lq*4 + r;
        float xhv = h2f(XB[(c*CKL+t)*CCH + (h<<6) + p]);
        YA[((c*CKL+t)<<8) + (h<<6) + p] = f2h(ya[mt][nt][r] + dval*xhv);
      }
    }
  }
}

// ---------------- K5: chunk-state scan (fp16 streams, fp32 accum) -----------
__global__ void k_scan(const u16* __restrict__ ST, u16* __restrict__ HP, const float* __restrict__ CDEC){
  int g = blockIdx.x*64 + threadIdx.x;
  int h = g>>12;
  float hp = 0.f;
  #pragma unroll 8
  for (int c=0;c<NCHK;c++){
    float dec = CDEC[(c<<2)+h];
    float sv = h2f(ST[g + (c<<14)]);
    HP[g + (c<<14)] = f2h(hp);
    hp = dec*hp + sv;
  }
}

// ---------------- K6: YB = exp(cum[t,h]) * C·H^T  (fp16 MFMA, all heads) ----
__global__ __launch_bounds__(256) void k_inter(const u16* __restrict__ XB, const float* __restrict__ CUM,
                                               const u16* __restrict__ HP, u16* __restrict__ YB){
  __shared__ u16 Cs[128*72];
  __shared__ u16 Hs[4*64*72];
  __shared__ float ex_s[4*128];
  int c = blockIdx.x;
  int tid = threadIdx.x, lane = tid&63, wid = tid>>6;
  int lm = lane&15, lq = lane>>4;
  for (int idx=tid; idx<1024; idx+=256){
    int t = idx>>3, b8 = idx&7;
    *(uint4*)&Cs[t*72 + b8*8] = *(const uint4*)(XB + (c*CKL+t)*CCH + 320 + b8*8);
  }
  for (int idx=tid; idx<2048; idx+=256){
    int h = idx>>9, p = (idx>>3)&63, b8 = idx&7;
    *(uint4*)&Hs[(h*64+p)*72 + b8*8] = *(const uint4*)(HP + ((c*4+h)*64+p)*64 + b8*8);
  }
  for (int idx=tid; idx<512; idx+=256){
    int h = idx>>7, t = idx&127;
    ex_s[h*128+t] = __expf(CUM[(c*CKL+t)*4+h]);
  }
  __syncthreads();
  int h = wid;
  const u16* Hh = &Hs[h*64*72];
  f32x4 acc[8][4] = {};
  for (int kt=0; kt<2; kt++){
    half8 af[8], bfv[4];
    #pragma unroll
    for (int mt=0;mt<8;mt++) af[mt] = *(const half8*)&Cs[(mt*16+lm)*72 + kt*32 + lq*8];
    #pragma unroll
    for (int nt=0;nt<4;nt++) bfv[nt] = *(const half8*)&Hh[(nt*16+lm)*72 + kt*32 + lq*8];
    #pragma unroll
    for (int mt=0;mt<8;mt++)
      #pragma unroll
      for (int nt=0;nt<4;nt++)
        acc[mt][nt] = __builtin_amdgcn_mfma_f32_16x16x32_f16(af[mt], bfv[nt], acc[mt][nt], 0,0,0);
  }
  #pragma unroll
  for (int mt=0;mt<8;mt++){
    #pragma unroll
    for (int r=0;r<4;r++){
      int t = mt*16 + lq*4 + r;
      float e = ex_s[h*128+t];
      u16* dst = &YB[((c*CKL+t)<<8) + (h<<6)];
      #pragma unroll
      for (int nt=0;nt<4;nt++){
        int p = nt*16 + lm;
        dst[p] = f2h(e*acc[mt][nt][r]);
      }
    }
  }
}

// ---------------- K7a: YH = fp16( rmsnorm((ya+yb)*silu(z)) * normw ) --------
__global__ __launch_bounds__(256) void k_ynorm(const u16* __restrict__ YA, const u16* __restrict__ YB,
                                               const u16* __restrict__ ZX, const float* __restrict__ nw,
                                               u16* __restrict__ YH){
  int t = blockIdx.x*4 + (threadIdx.x>>6);
  int lane = threadIdx.x&63;
  float a[4], b[4], z[4], u[4];
  up4(*(const uint2*)(YA + t*DIN + lane*4), a);
  up4(*(const uint2*)(YB + t*DIN + lane*4), b);
  up4(*(const uint2*)(ZX + t*NPROJ + lane*4), z);
  float4 w = *(const float4*)(nw + lane*4);
  float ss = 0.f;
  #pragma unroll
  for (int j=0;j<4;j++){ u[j] = (a[j]+b[j])*siluf_(z[j]); ss += u[j]*u[j]; }
  #pragma unroll
  for (int off=32; off; off>>=1) ss += __shfl_xor(ss, off, 64);
  float sc = rsqrtf(ss*(1.f/DIN)+1e-6f);
  float o[4] = { u[0]*sc*w.x, u[1]*sc*w.y, u[2]*sc*w.z, u[3]*sc*w.w };
  *(uint2*)(YH + t*DIN + lane*4) = pk4(o);
}

// ---------------- K7b: out GEMM + gate scatter (write run0, acc after) ------
__global__ __launch_bounds__(256) void k_gout_mfma(const u16* __restrict__ YH, const u16* __restrict__ WoT,
                                                   const float* __restrict__ G, float* __restrict__ GACC, int run){
  __shared__ u16 Ys[128*136];
  __shared__ u16 Ws[128*136];
  int t0 = blockIdx.x*128;
  int tid = threadIdx.x, lane = tid&63, wid = tid>>6;
  int lm = lane&15, lq = lane>>4;
  f32x4 acc[2][8] = {};
  for (int kb=0; kb<2; kb++){
    __syncthreads();
    for (int ch=tid; ch<2048; ch+=256){
      int row = ch>>4, c8 = ch&15;
      *(uint4*)&Ys[row*136 + c8*8] = *(const uint4*)(YH + (t0+row)*DIN + kb*128 + c8*8);
      *(uint4*)&Ws[row*136 + c8*8] = *(const uint4*)(WoT + row*DIN + kb*128 + c8*8);
    }
    __syncthreads();
    for (int kt=0; kt<4; kt++){
      half8 af[2], bfv[8];
      #pragma unroll
      for (int mt=0;mt<2;mt++) af[mt] = *(const half8*)&Ys[(wid*32+mt*16+lm)*136 + kt*32 + lq*8];
      #pragma unroll
      for (int nt=0;nt<8;nt++) bfv[nt] = *(const half8*)&Ws[(nt*16+lm)*136 + kt*32 + lq*8];
      #pragma unroll
      for (int mt=0;mt<2;mt++)
        #pragma unroll
        for (int nt=0;nt<8;nt++)
          acc[mt][nt] = __builtin_amdgcn_mfma_f32_16x16x32_f16(af[mt], bfv[nt], acc[mt][nt], 0,0,0);
    }
  }
  #pragma unroll
  for (int mt=0;mt<2;mt++){
    #pragma unroll
    for (int r=0;r<4;r++){
      int t = t0 + wid*32 + mt*16 + lq*4 + r;
      int sp = seq2sp(t, run);
      float g = G[run*LSEQ + sp];
      float* dst = &GACC[sp*CDIM];
      if (run==0){
        #pragma unroll
        for (int nt=0;nt<8;nt++) dst[nt*16+lm] = g*acc[mt][nt][r];
      } else {
        #pragma unroll
        for (int nt=0;nt<8;nt++) dst[nt*16+lm] += g*acc[mt][nt][r];
      }
    }
  }
}

// ---------------- K8: depthwise 3x3x3 conv, LDS-tiled -----------------------
__global__ __launch_bounds__(256) void k_dwconv(const float* __restrict__ XN, const float* __restrict__ w,
                                                const float* __restrict__ b, float* __restrict__ LC1){
  __shared__ float sm[3*34*40];
  int cc = blockIdx.x>>5, d = blockIdx.x&31;
  int tid = threadIdx.x;
  for (int i=tid; i<4080; i+=256) sm[i] = 0.f;
  __syncthreads();
  #pragma unroll
  for (int p=0;p<3;p++){
    int dz = d-1+p;
    if ((unsigned)dz<=31u){
      for (int idx=tid; idx<1024; idx+=256){
        int hh = idx>>5, ww = idx&31;
        sm[p*1360 + (hh+1)*40 + (ww+4)] = XN[cc*LSEQ + (dz<<10) + idx];
      }
    }
  }
  __syncthreads();
  float wreg[27];
  #pragma unroll
  for (int i=0;i<27;i++) wreg[i] = w[cc*27+i];
  float bias = b[cc];
  int h = tid>>3, w0 = (tid&7)*4;
  float4 acc = {bias,bias,bias,bias};
  #pragma unroll
  for (int p=0;p<3;p++){
    #pragma unroll
    for (int dy=0;dy<3;dy++){
      const float* row = &sm[p*1360 + (h+dy)*40 + 4];
      float left  = row[w0-1];
      float4 mid  = *(const float4*)&row[w0];
      float right = row[w0+4];
      float wa=wreg[p*9+dy*3+0], wb=wreg[p*9+dy*3+1], wc=wreg[p*9+dy*3+2];
      acc.x += wa*left  + wb*mid.x + wc*mid.y;
      acc.y += wa*mid.x + wb*mid.y + wc*mid.z;
      acc.z += wa*mid.y + wb*mid.z + wc*mid.w;
      acc.w += wa*mid.z + wb*mid.w + wc*right;
    }
  }
  *(float4*)&LC1[cc*LSEQ + (d<<10) + h*32 + w0] = acc;
}

// ---------------- K9: pointwise 128x128 + silu (fp16 MFMA) ------------------
__global__ __launch_bounds__(256) void k_pw(const float* __restrict__ LC1, const float* __restrict__ pw,
                                            const float* __restrict__ pwb, float* __restrict__ LC2){
  __shared__ u16 Ws[128*136];
  __shared__ u16 Bs[128*136];
  int s0 = blockIdx.x*128;
  int tid = threadIdx.x, lane = tid&63, wid = tid>>6;
  int lm = lane&15, lq = lane>>4;
  for (int idx=tid; idx<16384; idx+=256){
    int o = idx>>7, cc = idx&127;
    Ws[o*136+cc] = f2h(pw[idx]);
  }
  for (int idx=tid; idx<16384; idx+=256){
    int cc = idx>>7, n = idx&127;
    Bs[n*136+cc] = f2h(LC1[cc*LSEQ + s0 + n]);
  }
  __syncthreads();
  f32x4 acc[2][8] = {};
  for (int kt=0; kt<4; kt++){
    half8 af[2], bfv[8];
    #pragma unroll
    for (int mt=0;mt<2;mt++) af[mt] = *(const half8*)&Ws[(wid*32+mt*16+lm)*136 + kt*32 + lq*8];
    #pragma unroll
    for (int nt=0;nt<8;nt++) bfv[nt] = *(const half8*)&Bs[(nt*16+lm)*136 + kt*32 + lq*8];
    #pragma unroll
    for (int mt=0;mt<2;mt++)
      #pragma unroll
      for (int nt=0;nt<8;nt++)
        acc[mt][nt] = __builtin_amdgcn_mfma_f32_16x16x32_f16(af[mt], bfv[nt], acc[mt][nt], 0,0,0);
  }
  #pragma unroll
  for (int mt=0;mt<2;mt++){
    #pragma unroll
    for (int r=0;r<4;r++){
      int o = wid*32 + mt*16 + lq*4 + r;
      float bb = pwb[o];
      float* dst = &LC2[o*LSEQ + s0];
      #pragma unroll
      for (int nt=0;nt<8;nt++){
        int n = nt*16 + lm;
        dst[n] = siluf_(acc[mt][nt][r] + bb);
      }
    }
  }
}

// ---------------- K10: fused = a*g + (1-a)*lc  +  per-channel sum -----------
__global__ void k_fuse(const float* __restrict__ GACC, const float* __restrict__ LC2,
                       const float* __restrict__ alpha, float* __restrict__ FUSED,
                       float* __restrict__ MEANACC){
  __shared__ float tile[64*65];
  __shared__ float csum[64];
  int bs = blockIdx.x>>1, bc = blockIdx.x&1;
  int s0 = bs*64, c0 = bc*64;
  int tid = threadIdx.x;
  float a = alpha[0];
  if (tid<64) csum[tid] = 0.f;
  for (int idx=tid; idx<4096; idx+=256){
    int i = idx>>6, j = idx&63;
    tile[i*65+j] = GACC[(s0+i)*CDIM + c0+j];
  }
  __syncthreads();
  for (int idx=tid; idx<4096; idx+=256){
    int j = idx>>6, i = idx&63;
    float g = tile[i*65+j];
    float l = LC2[(c0+j)*LSEQ + s0+i];
    float f = a*g + (1.f-a)*l;
    FUSED[(c0+j)*LSEQ + s0+i] = f;
    atomicAdd(&csum[j], f);
  }
  __syncthreads();
  if (tid<64) atomicAdd(&MEANACC[c0+tid], csum[tid]);
}

// ---------------- K11: channel attention (mean scale folded in) -------------
__global__ void k_ca(const float* __restrict__ MEANACC, const float* __restrict__ w1, const float* __restrict__ b1,
                     const float* __restrict__ w2, const float* __restrict__ b2, float* __restrict__ SIG){
  __shared__ float y1[8];
  int tid = threadIdx.x;
  if (tid<8){
    float acc = b1[tid];
    for (int c=0;c<128;c++) acc += w1[tid*128+c]*(MEANACC[c]*(1.f/LSEQ));
    y1[tid] = (acc>=0.f)? acc : 0.1f*acc;
  }
  __syncthreads();
  float acc = b2[tid];
  #pragma unroll
  for (int o=0;o<8;o++) acc += w2[tid*8+o]*y1[o];
  SIG[tid] = sigmoidf_(acc);
}

// ---------------- K12: out = x + fused * sigmoid(yc) ------------------------
__global__ void k_final(const float* __restrict__ x, const float* __restrict__ F, const float* __restrict__ SIG,
                        float* __restrict__ out){
  int idx = blockIdx.x*256 + threadIdx.x;
  int cc = idx>>15;
  out[idx] = x[idx] + F[idx]*SIG[cc];
}

extern "C" void kernel_launch(void* const* d_in, const int* in_sizes, int n_in,
                              void* d_out, int out_size, void* d_ws, size_t ws_size,
                              hipStream_t stream){
  (void)in_sizes; (void)n_in; (void)out_size; (void)ws_size;
  const float* x       = (const float*)d_in[0];
  const float* norm_w  = (const float*)d_in[1];
  const float* gate_w  = (const float*)d_in[2];
  const float* gate_b  = (const float*)d_in[3];
  const float* loc_dw_w= (const float*)d_in[28];
  const float* loc_dw_b= (const float*)d_in[29];
  const float* loc_pw_w= (const float*)d_in[30];
  const float* loc_pw_b= (const float*)d_in[31];
  const float* ca_w1   = (const float*)d_in[32];
  const float* ca_b1   = (const float*)d_in[33];
  const float* ca_w2   = (const float*)d_in[34];
  const float* ca_b2   = (const float*)d_in[35];
  const float* alpha   = (const float*)d_in[36];

  float* W     = (float*)d_ws;
  float* XN    = W;                         // 4,194,304
  float* GATES = XN    + 4194304;           //   196,608
  float* GACC  = GATES + 196608;            // 4,194,304
  u16*   ZX    = (u16*)(GACC + 4194304);    // 21,102,592 u16
  u16*   XB    = (u16*)(GACC + 4194304 + 10551296);   // 12,582,912 u16
  float* DT    = GACC + 4194304 + 10551296 + 6291456; // 131,072
  float* CUM   = DT    + 131072;            //   131,072
  float* CDEC  = CUM   + 131072;            //     1,024
  float* STreg = CDEC  + 1024;              // 4,194,304 fl region (ST16 / YH alias)
  float* Y     = STreg + 4194304;           // 8,388,608 fl = YA/YB fp16
  float* LC1   = Y     + 8388608;           // 4,194,304 (HPREV16 alias)
  float* LC2   = LC1   + 4194304;           // 4,194,304
  float* MEAN  = LC2   + 4194304;           //       128
  float* SIG   = MEAN  + 128;               //       128
  u16*   XNT   = (u16*)(SIG + 128);         // 4,194,304 u16
  u16*   WinT  = XNT + 4194304;             //    81,920 u16
  u16*   WoT   = WinT + 98304;              //    32,768 u16
  u16*   ST16  = (u16*)STreg;               // 4,194,304 u16
  u16*   YH    = (u16*)STreg;               // alias (ST dead after k_inter)
  u16*   YA    = (u16*)Y;                   // 8,388,608 u16
  u16*   YB    = YA + 8388608;              // 8,388,608 u16
  u16*   HP16  = (u16*)LC1;                 // 4,194,304 u16

  hipMemsetAsync(MEAN, 0, 128*sizeof(float), stream);
  k_xng<<<128,256,0,stream>>>(x, norm_w, gate_w, gate_b, XN, GATES);

  for (int r=0;r<6;r++){
    int m = r>>1;
    const float* Win   = (const float*)d_in[4 + m*8 + 0];
    const float* convw = (const float*)d_in[4 + m*8 + 1];
    const float* convb = (const float*)d_in[4 + m*8 + 2];
    const float* dtb   = (const float*)d_in[4 + m*8 + 3];
    const float* Alog  = (const float*)d_in[4 + m*8 + 4];
    const float* Dp    = (const float*)d_in[4 + m*8 + 5];
    const float* nw2   = (const float*)d_in[4 + m*8 + 6];
    const float* Wout  = (const float*)d_in[4 + m*8 + 7];
    if ((r&1)==0){
      k_permute<<<1024,256,0,stream>>>(XN, XNT, m);
      k_prepw  <<<320,256,0,stream>>>(Win, WinT);
      k_prewo  <<<128,256,0,stream>>>(Wout, WoT);
    }
    k_gin_mfma<<<dim3(5,256),256,0,stream>>>(XNT, WinT, ZX, r&1);
    k_conv    <<<1024,384,0,stream>>>(ZX, convw, convb, XB);
    k_dtcum   <<<256,256,0,stream>>>(XNT, Win, dtb, Alog, DT, CUM, CDEC, r&1);
    k_chunk   <<<1024,256,0,stream>>>(XB, DT, CUM, Dp, YA, ST16);
    k_scan    <<<256,64,0,stream>>>(ST16, HP16, CDEC);
    k_inter   <<<256,256,0,stream>>>(XB, CUM, HP16, YB);
    k_ynorm   <<<8192,256,0,stream>>>(YA, YB, ZX, nw2, YH);
    k_gout_mfma<<<256,256,0,stream>>>(YH, WoT, GATES, GACC, r);
  }

  k_dwconv<<<4096,256,0,stream>>>(XN, loc_dw_w, loc_dw_b, LC1);
  k_pw    <<<256,256,0,stream>>>(LC1, loc_pw_w, loc_pw_b, LC2);
  k_fuse  <<<1024,256,0,stream>>>(GACC, LC2, alpha, LC1, MEAN);
  k_ca    <<<1,128,0,stream>>>(MEAN, ca_w1, ca_b1, ca_w2, ca_b2, SIG);
  k_final <<<16384,256,0,stream>>>(x, LC1, SIG, (float*)d_out);
}

// Round 11
// 1127.811 us; speedup vs baseline: 1.0195x; 1.0195x over previous
//
#include <hip/hip_runtime.h>

// OmniMambaBlock — round 11: k_fuse wave-reduce + PSUM (no atomics), k_msum.

typedef unsigned short u16;
typedef unsigned int   u32;
typedef __attribute__((ext_vector_type(8))) short short8;      // bf16x8
typedef __attribute__((ext_vector_type(8))) _Float16 half8;    // fp16x8
typedef __attribute__((ext_vector_type(4))) float f32x4;

#define LSEQ 32768
#define CDIM 128
#define NPROJ 644
#define CCH 384
#define DIN 256
#define NHD 4
#define CKL 128
#define NCHK 256

__device__ __forceinline__ float b2f(u16 u){ u32 x=((u32)u)<<16; float f; __builtin_memcpy(&f,&x,4); return f; }
__device__ __forceinline__ u16 f2b(float f){ u32 x; __builtin_memcpy(&x,&f,4); x += 0x7fffu + ((x>>16)&1u); return (u16)(x>>16); }
__device__ __forceinline__ u16 f2h(float v){ _Float16 h=(_Float16)v; u16 b; __builtin_memcpy(&b,&h,2); return b; }
__device__ __forceinline__ float h2f(u16 b){ _Float16 h; __builtin_memcpy(&h,&b,2); return (float)h; }
__device__ __forceinline__ void up4(uint2 v, float* o){
  union { uint2 u; _Float16 h[4]; } c; c.u = v;
  o[0]=(float)c.h[0]; o[1]=(float)c.h[1]; o[2]=(float)c.h[2]; o[3]=(float)c.h[3];
}
__device__ __forceinline__ uint2 pk4(const float* o){
  union { uint2 u; _Float16 h[4]; } c;
  c.h[0]=(_Float16)o[0]; c.h[1]=(_Float16)o[1]; c.h[2]=(_Float16)o[2]; c.h[3]=(_Float16)o[3];
  return c.u;
}
__device__ __forceinline__ float sigmoidf_(float v){ return 1.f/(1.f+__expf(-v)); }
__device__ __forceinline__ float siluf_(float v){ return v*sigmoidf_(v); }
__device__ __forceinline__ float softplusf_(float v){ return (v>20.f)? v : log1pf(__expf(v)); }

__device__ __forceinline__ int seq2sp(int t, int run){
  int te = (run&1) ? (LSEQ-1-t) : t;
  int a = te>>10, b=(te>>5)&31, c=te&31;
  int d,h,w;
  switch(run>>1){
    case 0: d=a; h=b; w=c; break;
    case 1: h=a; d=b; w=c; break;
    default: w=a; d=b; h=c; break;
  }
  return (d<<10)|(h<<5)|w;
}

// ---------------- K1: fused rmsnorm + gate softmax --------------------------
__global__ void k_xng(const float* __restrict__ x, const float* __restrict__ nw,
                      const float* __restrict__ gw, const float* __restrict__ gb,
                      float* __restrict__ XN, float* __restrict__ G){
  int s = blockIdx.x*256 + threadIdx.x;
  float ss = 0.f;
  #pragma unroll 8
  for (int c=0;c<CDIM;c++){ float v=x[c*LSEQ+s]; ss += v*v; }
  float sc = rsqrtf(ss*(1.f/CDIM)+1e-6f);
  float a[6];
  #pragma unroll
  for (int j=0;j<6;j++) a[j]=gb[j];
  #pragma unroll 4
  for (int c=0;c<CDIM;c++){
    float xnv = x[c*LSEQ+s]*sc*nw[c];
    XN[c*LSEQ+s] = xnv;
    #pragma unroll
    for (int j=0;j<6;j++) a[j] += xnv*gw[c*6+j];
  }
  float m=a[0];
  #pragma unroll
  for (int j=1;j<6;j++) m = fmaxf(m,a[j]);
  float e[6], ssum=0.f;
  #pragma unroll
  for (int j=0;j<6;j++){ e[j]=__expf(a[j]-m); ssum+=e[j]; }
  float inv = 1.f/ssum;
  #pragma unroll
  for (int j=0;j<6;j++) G[j*LSEQ+s] = e[j]*inv;
}

// ---------------- K_perm: XNT[t][c] bf16, sequence-ordered ------------------
__global__ __launch_bounds__(256) void k_permute(const float* __restrict__ XN, u16* __restrict__ XNT, int dir){
  __shared__ u16 TS[128*34];
  int a = blockIdx.x>>5, b = blockIdx.x&31;
  int tid = threadIdx.x;
  int spa = (dir==1)? b : a;
  int spb = (dir==1)? a : b;
  int spbase = spa*1024 + spb*32;
  for (int idx=tid; idx<4096; idx+=256){
    int c = idx>>5, i = idx&31;
    TS[c*34+i] = f2b(XN[c*LSEQ + spbase + i]);
  }
  __syncthreads();
  for (int idx=tid; idx<4096; idx+=256){
    int i = idx>>7, c = idx&127;
    int t = (dir==2) ? (i*1024 + a*32 + b) : (a*1024 + b*32 + i);
    XNT[t*128 + c] = TS[c*34+i];
  }
}

// ---------------- K_prepw: WinT[j][k] bf16, j<640 ---------------------------
__global__ void k_prepw(const float* __restrict__ Win, u16* __restrict__ WinT){
  int idx = blockIdx.x*256 + threadIdx.x;   // 640*128 = 81920
  int j = idx>>7, k = idx&127;
  WinT[idx] = f2b(Win[k*NPROJ + j]);
}

// ---------------- K_prewo: WoT[c][k] fp16 (Wout transposed) -----------------
__global__ void k_prewo(const float* __restrict__ Wout, u16* __restrict__ WoT){
  int idx = blockIdx.x*256 + threadIdx.x;
  int c = idx>>8, k = idx&255;
  WoT[idx] = f2h(Wout[k*CDIM + c]);
}

// ---------------- K2: ZX[t,j<640] = XNT[t,:]·WinT[j,:]  (bf16 MFMA) ---------
__global__ __launch_bounds__(256) void k_gin_mfma(const u16* __restrict__ XNT, const u16* __restrict__ WinT,
                                                  u16* __restrict__ ZX, int flip){
  __shared__ u16 Asb[128*136];
  __shared__ u16 Bsb[128*136];
  int j0 = blockIdx.x*128, t0 = blockIdx.y*128;
  int tid = threadIdx.x;
  for (int ch = tid; ch < 2048; ch += 256){
    int row = ch>>4, c8 = ch&15;
    int tg = flip ? (LSEQ-1-(t0+row)) : (t0+row);
    uint4 av = *(const uint4*)(XNT + tg*128 + c8*8);
    *(uint4*)(&Asb[row*136 + c8*8]) = av;
    uint4 bv = *(const uint4*)(WinT + (j0+row)*128 + c8*8);
    *(uint4*)(&Bsb[row*136 + c8*8]) = bv;
  }
  __syncthreads();
  int lane = tid&63, wid = tid>>6;
  int wm = (wid>>1)*64, wn = (wid&1)*64;
  int lm = lane&15, lq = lane>>4;
  f32x4 acc[4][4] = {};
  for (int kt=0; kt<4; kt++){
    short8 af[4], bf[4];
    #pragma unroll
    for (int mt=0;mt<4;mt++) af[mt] = *(const short8*)(&Asb[(wm+mt*16+lm)*136 + kt*32 + lq*8]);
    #pragma unroll
    for (int nt=0;nt<4;nt++) bf[nt] = *(const short8*)(&Bsb[(wn+nt*16+lm)*136 + kt*32 + lq*8]);
    #pragma unroll
    for (int mt=0;mt<4;mt++)
      #pragma unroll
      for (int nt=0;nt<4;nt++)
        acc[mt][nt] = __builtin_amdgcn_mfma_f32_16x16x32_bf16(af[mt], bf[nt], acc[mt][nt], 0,0,0);
  }
  #pragma unroll
  for (int mt=0;mt<4;mt++){
    #pragma unroll
    for (int nt=0;nt<4;nt++){
      int j = j0 + wn + nt*16 + lm;
      #pragma unroll
      for (int r=0;r<4;r++){
        int t = t0 + wm + mt*16 + lq*4 + r;
        ZX[t*NPROJ + j] = f2h(acc[mt][nt][r]);
      }
    }
  }
}

// ---------------- K3a: causal depthwise conv1d K=4 + silu -> XB fp16 --------
__global__ __launch_bounds__(384) void k_conv(const u16* __restrict__ ZX, const float* __restrict__ cw,
                                              const float* __restrict__ cb, u16* __restrict__ XB){
  __shared__ u16 smc[35*384];
  int t0 = blockIdx.x*32;
  int tid = threadIdx.x;
  for (int idx=tid; idx<13440; idx+=384){
    int j = idx/384, chh = idx - j*384;
    int t = t0-3+j;
    smc[idx] = (t>=0)? ZX[t*NPROJ + 256 + chh] : (u16)0;
  }
  __syncthreads();
  int ch = tid;
  float w0=cw[ch*4], w1=cw[ch*4+1], w2=cw[ch*4+2], w3=cw[ch*4+3], bb=cb[ch];
  for (int i=0;i<32;i++){
    float acc = w0*h2f(smc[i*384+ch]) + w1*h2f(smc[(i+1)*384+ch])
              + w2*h2f(smc[(i+2)*384+ch]) + w3*h2f(smc[(i+3)*384+ch]) + bb;
    XB[(t0+i)*CCH + ch] = f2h(siluf_(acc));
  }
}

// ---------------- K3b: dt = softplus(XNT·Win_dt + b) + chunk cumsum ---------
__global__ __launch_bounds__(256) void k_dtcum(const u16* __restrict__ XNT, const float* __restrict__ Win,
                                               const float* __restrict__ dtb, const float* __restrict__ Alog,
                                               float* __restrict__ DT, float* __restrict__ CUM,
                                               float* __restrict__ CDEC, int flip){
  int g = blockIdx.x*4 + (threadIdx.x>>6);
  int lane = threadIdx.x&63;
  int c = g>>2, h = g&3;
  float A = -__expf(Alog[h]);
  float bias = dtb[h];
  int t0 = c*CKL + lane*2;
  int tg0 = flip ? (LSEQ-1-t0) : t0;
  int tg1 = flip ? (LSEQ-1-(t0+1)) : (t0+1);
  const u16* row0 = XNT + tg0*128;
  const u16* row1 = XNT + tg1*128;
  float r0 = 0.f, r1 = 0.f;
  for (int k8=0; k8<16; k8++){
    uint4 a0 = *(const uint4*)(row0 + k8*8);
    uint4 a1 = *(const uint4*)(row1 + k8*8);
    const u16* p0 = (const u16*)&a0;
    const u16* p1 = (const u16*)&a1;
    #pragma unroll
    for (int j=0;j<8;j++){
      float wv = Win[(k8*8+j)*NPROJ + 640 + h];
      r0 += b2f(p0[j])*wv;
      r1 += b2f(p1[j])*wv;
    }
  }
  float d0 = softplusf_(r0+bias), d1 = softplusf_(r1+bias);
  DT[t0*4+h] = d0; DT[(t0+1)*4+h] = d1;
  float e0 = d0*A, e1 = d1*A;
  float s = e0+e1;
  #pragma unroll
  for (int off=1; off<64; off<<=1){
    float v = __shfl_up(s, off, 64);
    if (lane>=off) s += v;
  }
  CUM[t0*4+h] = s - e1;
  CUM[(t0+1)*4+h] = s;
  float tot = __shfl(s, 63, 64);
  if (lane==0) CDEC[c*4+h] = __expf(tot);
}

// ---------------- K4: per (chunk,head) — CUM from global --------------------
__global__ __launch_bounds__(256) void k_chunk(const u16* __restrict__ XB, const float* __restrict__ DT,
                                               const float* __restrict__ CUM, const float* __restrict__ Dp,
                                               u16* __restrict__ YA, u16* __restrict__ ST){
  __shared__ u16 sh[27136];
  u16* Cs   = sh;           // [128][72]
  u16* Bsm  = sh + 9216;    // [128][72]
  u16* BdeT = sh;           // [64][136] overlays Cs after CB
  u16* Mh   = sh;           // [128][136] overlays Cs+Bsm after S
  u16* Xsh  = sh + 18432;   // [64][136]

  int bid = blockIdx.x; int c = bid>>2, h = bid&3;
  int tid = threadIdx.x, lane = tid&63, wid = tid>>6;
  int lm = lane&15, lq = lane>>4;
  const float* CUMc = CUM + (c*CKL)*4 + h;

  for (int idx=tid; idx<1024; idx+=256){
    int t = idx>>3, b8 = idx&7;
    const u16* row = XB + (c*CKL+t)*CCH;
    *(uint4*)&Cs[t*72 + b8*8]  = *(const uint4*)(row + 320 + b8*8);
    *(uint4*)&Bsm[t*72 + b8*8] = *(const uint4*)(row + 256 + b8*8);
  }
  for (int idx=tid; idx<8192; idx+=256){
    int t = idx>>6, n = idx&63;
    float xv = h2f(XB[(c*CKL+t)*CCH + h*64 + n]) * DT[(c*CKL+t)*4 + h];
    Xsh[n*136 + t] = f2h(xv);
  }
  float cum_t[2][4];
  #pragma unroll
  for (int mt=0;mt<2;mt++)
    #pragma unroll
    for (int r=0;r<4;r++) cum_t[mt][r] = CUMc[(wid*32+mt*16+lq*4+r)*4];
  float cl = CUMc[127*4];
  __syncthreads();

  f32x4 cbac[2][8] = {};
  for (int kt=0; kt<2; kt++){
    half8 af0 = *(const half8*)&Cs[(wid*32+ 0+lm)*72 + kt*32 + lq*8];
    half8 af1 = *(const half8*)&Cs[(wid*32+16+lm)*72 + kt*32 + lq*8];
    #pragma unroll
    for (int nt=0;nt<8;nt++){
      if (nt <= wid*2+1){
        half8 bfv = *(const half8*)&Bsm[(nt*16+lm)*72 + kt*32 + lq*8];
        if (nt <= wid*2)
          cbac[0][nt] = __builtin_amdgcn_mfma_f32_16x16x32_f16(af0, bfv, cbac[0][nt], 0,0,0);
        cbac[1][nt] = __builtin_amdgcn_mfma_f32_16x16x32_f16(af1, bfv, cbac[1][nt], 0,0,0);
      }
    }
  }
  __syncthreads();

  for (int idx=tid; idx<8192; idx+=256){
    int s = idx&127, n = idx>>7;
    float de = __expf(cl - CUMc[s*4]);
    BdeT[n*136+s] = f2h(h2f(Bsm[s*72+n]) * de);
  }
  __syncthreads();

  f32x4 sa[4] = {};
  for (int kt=0; kt<4; kt++){
    half8 aa = *(const half8*)&Xsh[(wid*16+lm)*136 + kt*32 + lq*8];
    #pragma unroll
    for (int nt=0;nt<4;nt++){
      half8 bfv = *(const half8*)&BdeT[(nt*16+lm)*136 + kt*32 + lq*8];
      sa[nt] = __builtin_amdgcn_mfma_f32_16x16x32_f16(aa, bfv, sa[nt], 0,0,0);
    }
  }
  #pragma unroll
  for (int nt=0;nt<4;nt++){
    int n = nt*16 + lm;
    #pragma unroll
    for (int r=0;r<4;r++){
      int p = wid*16 + lq*4 + r;
      ST[((c*4+h)*64 + p)*64 + n] = f2h(sa[nt][r]);
    }
  }
  __syncthreads();

  #pragma unroll
  for (int mt=0;mt<2;mt++){
    int tb = wid*32 + mt*16;
    int diag = wid*2 + mt;
    int hi = wid*2 + 1;
    #pragma unroll
    for (int nt=0;nt<8;nt++){
      if (nt > hi) break;
      int s = nt*16 + lm;
      if (nt > diag){
        #pragma unroll
        for (int r=0;r<4;r++) Mh[(tb+lq*4+r)*136+s] = 0;
      } else {
        float cums = CUMc[s*4];
        if (nt == diag){
          #pragma unroll
          for (int r=0;r<4;r++){
            int t = tb + lq*4 + r;
            float m = (s<=t)? cbac[mt][nt][r]*__expf(cum_t[mt][r]-cums) : 0.f;
            Mh[t*136+s] = f2h(m);
          }
        } else {
          #pragma unroll
          for (int r=0;r<4;r++){
            int t = tb + lq*4 + r;
            Mh[t*136+s] = f2h(cbac[mt][nt][r]*__expf(cum_t[mt][r]-cums));
          }
        }
      }
    }
  }

  f32x4 ya[2][4] = {};
  for (int kt=0; kt<=wid; kt++){
    half8 af[2], bfv[4];
    #pragma unroll
    for (int mt=0;mt<2;mt++) af[mt] = *(const half8*)&Mh[(wid*32+mt*16+lm)*136 + kt*32 + lq*8];
    #pragma unroll
    for (int nt=0;nt<4;nt++) bfv[nt] = *(const half8*)&Xsh[(nt*16+lm)*136 + kt*32 + lq*8];
    #pragma unroll
    for (int mt=0;mt<2;mt++)
      #pragma unroll
      for (int nt=0;nt<4;nt++)
        ya[mt][nt] = __builtin_amdgcn_mfma_f32_16x16x32_f16(af[mt], bfv[nt], ya[mt][nt], 0,0,0);
  }
  float dval = Dp[h];
  #pragma unroll
  for (int mt=0;mt<2;mt++){
    #pragma unroll
    for (int nt=0;nt<4;nt++){
      int p = nt*16 + lm;
      #pragma unroll
      for (int r=0;r<4;r++){
        int t = wid*32 + mt*16 + lq*4 + r;
        float xhv = h2f(XB[(c*CKL+t)*CCH + (h<<6) + p]);
        YA[((c*CKL+t)<<8) + (h<<6) + p] = f2h(ya[mt][nt][r] + dval*xhv);
      }
    }
  }
}

// ---------------- K5: chunk-state scan (fp16 streams, fp32 accum) -----------
__global__ void k_scan(const u16* __restrict__ ST, u16* __restrict__ HP, const float* __restrict__ CDEC){
  int g = blockIdx.x*64 + threadIdx.x;
  int h = g>>12;
  float hp = 0.f;
  #pragma unroll 8
  for (int c=0;c<NCHK;c++){
    float dec = CDEC[(c<<2)+h];
    float sv = h2f(ST[g + (c<<14)]);
    HP[g + (c<<14)] = f2h(hp);
    hp = dec*hp + sv;
  }
}

// ---------------- K6: YB = exp(cum[t,h]) * C·H^T  (fp16 MFMA, all heads) ----
__global__ __launch_bounds__(256) void k_inter(const u16* __restrict__ XB, const float* __restrict__ CUM,
                                               const u16* __restrict__ HP, u16* __restrict__ YB){
  __shared__ u16 Cs[128*72];
  __shared__ u16 Hs[4*64*72];
  __shared__ float ex_s[4*128];
  int c = blockIdx.x;
  int tid = threadIdx.x, lane = tid&63, wid = tid>>6;
  int lm = lane&15, lq = lane>>4;
  for (int idx=tid; idx<1024; idx+=256){
    int t = idx>>3, b8 = idx&7;
    *(uint4*)&Cs[t*72 + b8*8] = *(const uint4*)(XB + (c*CKL+t)*CCH + 320 + b8*8);
  }
  for (int idx=tid; idx<2048; idx+=256){
    int h = idx>>9, p = (idx>>3)&63, b8 = idx&7;
    *(uint4*)&Hs[(h*64+p)*72 + b8*8] = *(const uint4*)(HP + ((c*4+h)*64+p)*64 + b8*8);
  }
  for (int idx=tid; idx<512; idx+=256){
    int h = idx>>7, t = idx&127;
    ex_s[h*128+t] = __expf(CUM[(c*CKL+t)*4+h]);
  }
  __syncthreads();
  int h = wid;
  const u16* Hh = &Hs[h*64*72];
  f32x4 acc[8][4] = {};
  for (int kt=0; kt<2; kt++){
    half8 af[8], bfv[4];
    #pragma unroll
    for (int mt=0;mt<8;mt++) af[mt] = *(const half8*)&Cs[(mt*16+lm)*72 + kt*32 + lq*8];
    #pragma unroll
    for (int nt=0;nt<4;nt++) bfv[nt] = *(const half8*)&Hh[(nt*16+lm)*72 + kt*32 + lq*8];
    #pragma unroll
    for (int mt=0;mt<8;mt++)
      #pragma unroll
      for (int nt=0;nt<4;nt++)
        acc[mt][nt] = __builtin_amdgcn_mfma_f32_16x16x32_f16(af[mt], bfv[nt], acc[mt][nt], 0,0,0);
  }
  #pragma unroll
  for (int mt=0;mt<8;mt++){
    #pragma unroll
    for (int r=0;r<4;r++){
      int t = mt*16 + lq*4 + r;
      float e = ex_s[h*128+t];
      u16* dst = &YB[((c*CKL+t)<<8) + (h<<6)];
      #pragma unroll
      for (int nt=0;nt<4;nt++){
        int p = nt*16 + lm;
        dst[p] = f2h(e*acc[mt][nt][r]);
      }
    }
  }
}

// ---------------- K7a: YH = fp16( rmsnorm((ya+yb)*silu(z)) * normw ) --------
__global__ __launch_bounds__(256) void k_ynorm(const u16* __restrict__ YA, const u16* __restrict__ YB,
                                               const u16* __restrict__ ZX, const float* __restrict__ nw,
                                               u16* __restrict__ YH){
  int t = blockIdx.x*4 + (threadIdx.x>>6);
  int lane = threadIdx.x&63;
  float a[4], b[4], z[4], u[4];
  up4(*(const uint2*)(YA + t*DIN + lane*4), a);
  up4(*(const uint2*)(YB + t*DIN + lane*4), b);
  up4(*(const uint2*)(ZX + t*NPROJ + lane*4), z);
  float4 w = *(const float4*)(nw + lane*4);
  float ss = 0.f;
  #pragma unroll
  for (int j=0;j<4;j++){ u[j] = (a[j]+b[j])*siluf_(z[j]); ss += u[j]*u[j]; }
  #pragma unroll
  for (int off=32; off; off>>=1) ss += __shfl_xor(ss, off, 64);
  float sc = rsqrtf(ss*(1.f/DIN)+1e-6f);
  float o[4] = { u[0]*sc*w.x, u[1]*sc*w.y, u[2]*sc*w.z, u[3]*sc*w.w };
  *(uint2*)(YH + t*DIN + lane*4) = pk4(o);
}

// ---------------- K7b: out GEMM + gate scatter (write run0, acc after) ------
__global__ __launch_bounds__(256) void k_gout_mfma(const u16* __restrict__ YH, const u16* __restrict__ WoT,
                                                   const float* __restrict__ G, float* __restrict__ GACC, int run){
  __shared__ u16 Ys[128*136];
  __shared__ u16 Ws[128*136];
  int t0 = blockIdx.x*128;
  int tid = threadIdx.x, lane = tid&63, wid = tid>>6;
  int lm = lane&15, lq = lane>>4;
  f32x4 acc[2][8] = {};
  for (int kb=0; kb<2; kb++){
    __syncthreads();
    for (int ch=tid; ch<2048; ch+=256){
      int row = ch>>4, c8 = ch&15;
      *(uint4*)&Ys[row*136 + c8*8] = *(const uint4*)(YH + (t0+row)*DIN + kb*128 + c8*8);
      *(uint4*)&Ws[row*136 + c8*8] = *(const uint4*)(WoT + row*DIN + kb*128 + c8*8);
    }
    __syncthreads();
    for (int kt=0; kt<4; kt++){
      half8 af[2], bfv[8];
      #pragma unroll
      for (int mt=0;mt<2;mt++) af[mt] = *(const half8*)&Ys[(wid*32+mt*16+lm)*136 + kt*32 + lq*8];
      #pragma unroll
      for (int nt=0;nt<8;nt++) bfv[nt] = *(const half8*)&Ws[(nt*16+lm)*136 + kt*32 + lq*8];
      #pragma unroll
      for (int mt=0;mt<2;mt++)
        #pragma unroll
        for (int nt=0;nt<8;nt++)
          acc[mt][nt] = __builtin_amdgcn_mfma_f32_16x16x32_f16(af[mt], bfv[nt], acc[mt][nt], 0,0,0);
    }
  }
  #pragma unroll
  for (int mt=0;mt<2;mt++){
    #pragma unroll
    for (int r=0;r<4;r++){
      int t = t0 + wid*32 + mt*16 + lq*4 + r;
      int sp = seq2sp(t, run);
      float g = G[run*LSEQ + sp];
      float* dst = &GACC[sp*CDIM];
      if (run==0){
        #pragma unroll
        for (int nt=0;nt<8;nt++) dst[nt*16+lm] = g*acc[mt][nt][r];
      } else {
        #pragma unroll
        for (int nt=0;nt<8;nt++) dst[nt*16+lm] += g*acc[mt][nt][r];
      }
    }
  }
}

// ---------------- K8: depthwise 3x3x3 conv, LDS-tiled -----------------------
__global__ __launch_bounds__(256) void k_dwconv(const float* __restrict__ XN, const float* __restrict__ w,
                                                const float* __restrict__ b, float* __restrict__ LC1){
  __shared__ float sm[3*34*40];
  int cc = blockIdx.x>>5, d = blockIdx.x&31;
  int tid = threadIdx.x;
  for (int i=tid; i<4080; i+=256) sm[i] = 0.f;
  __syncthreads();
  #pragma unroll
  for (int p=0;p<3;p++){
    int dz = d-1+p;
    if ((unsigned)dz<=31u){
      for (int idx=tid; idx<1024; idx+=256){
        int hh = idx>>5, ww = idx&31;
        sm[p*1360 + (hh+1)*40 + (ww+4)] = XN[cc*LSEQ + (dz<<10) + idx];
      }
    }
  }
  __syncthreads();
  float wreg[27];
  #pragma unroll
  for (int i=0;i<27;i++) wreg[i] = w[cc*27+i];
  float bias = b[cc];
  int h = tid>>3, w0 = (tid&7)*4;
  float4 acc = {bias,bias,bias,bias};
  #pragma unroll
  for (int p=0;p<3;p++){
    #pragma unroll
    for (int dy=0;dy<3;dy++){
      const float* row = &sm[p*1360 + (h+dy)*40 + 4];
      float left  = row[w0-1];
      float4 mid  = *(const float4*)&row[w0];
      float right = row[w0+4];
      float wa=wreg[p*9+dy*3+0], wb=wreg[p*9+dy*3+1], wc=wreg[p*9+dy*3+2];
      acc.x += wa*left  + wb*mid.x + wc*mid.y;
      acc.y += wa*mid.x + wb*mid.y + wc*mid.z;
      acc.z += wa*mid.y + wb*mid.z + wc*mid.w;
      acc.w += wa*mid.z + wb*mid.w + wc*right;
    }
  }
  *(float4*)&LC1[cc*LSEQ + (d<<10) + h*32 + w0] = acc;
}

// ---------------- K9: pointwise 128x128 + silu (fp16 MFMA) ------------------
__global__ __launch_bounds__(256) void k_pw(const float* __restrict__ LC1, const float* __restrict__ pw,
                                            const float* __restrict__ pwb, float* __restrict__ LC2){
  __shared__ u16 Ws[128*136];
  __shared__ u16 Bs[128*136];
  int s0 = blockIdx.x*128;
  int tid = threadIdx.x, lane = tid&63, wid = tid>>6;
  int lm = lane&15, lq = lane>>4;
  for (int idx=tid; idx<16384; idx+=256){
    int o = idx>>7, cc = idx&127;
    Ws[o*136+cc] = f2h(pw[idx]);
  }
  for (int idx=tid; idx<16384; idx+=256){
    int cc = idx>>7, n = idx&127;
    Bs[n*136+cc] = f2h(LC1[cc*LSEQ + s0 + n]);
  }
  __syncthreads();
  f32x4 acc[2][8] = {};
  for (int kt=0; kt<4; kt++){
    half8 af[2], bfv[8];
    #pragma unroll
    for (int mt=0;mt<2;mt++) af[mt] = *(const half8*)&Ws[(wid*32+mt*16+lm)*136 + kt*32 + lq*8];
    #pragma unroll
    for (int nt=0;nt<8;nt++) bfv[nt] = *(const half8*)&Bs[(nt*16+lm)*136 + kt*32 + lq*8];
    #pragma unroll
    for (int mt=0;mt<2;mt++)
      #pragma unroll
      for (int nt=0;nt<8;nt++)
        acc[mt][nt] = __builtin_amdgcn_mfma_f32_16x16x32_f16(af[mt], bfv[nt], acc[mt][nt], 0,0,0);
  }
  #pragma unroll
  for (int mt=0;mt<2;mt++){
    #pragma unroll
    for (int r=0;r<4;r++){
      int o = wid*32 + mt*16 + lq*4 + r;
      float bb = pwb[o];
      float* dst = &LC2[o*LSEQ + s0];
      #pragma unroll
      for (int nt=0;nt<8;nt++){
        int n = nt*16 + lm;
        dst[n] = siluf_(acc[mt][nt][r] + bb);
      }
    }
  }
}

// ---------------- K10: fused = a*g + (1-a)*lc  + per-block column sums ------
__global__ void k_fuse(const float* __restrict__ GACC, const float* __restrict__ LC2,
                       const float* __restrict__ alpha, float* __restrict__ FUSED,
                       float* __restrict__ PSUM){
  __shared__ float tile[64*65];
  __shared__ float csum[64];
  int bs = blockIdx.x>>1, bc = blockIdx.x&1;
  int s0 = bs*64, c0 = bc*64;
  int tid = threadIdx.x, lane = tid&63;
  float a = alpha[0];
  for (int idx=tid; idx<4096; idx+=256){
    int i = idx>>6, j = idx&63;
    tile[i*65+j] = GACC[(s0+i)*CDIM + c0+j];
  }
  __syncthreads();
  // each (wave,k) handles a distinct column j = wid + 4k; i = lane
  #pragma unroll 4
  for (int k=0;k<16;k++){
    int idx = tid + k*256;
    int j = idx>>6, i = idx&63;
    float g = tile[i*65+j];
    float l = LC2[(c0+j)*LSEQ + s0+i];
    float f = a*g + (1.f-a)*l;
    FUSED[(c0+j)*LSEQ + s0+i] = f;
    #pragma unroll
    for (int off=32; off; off>>=1) f += __shfl_xor(f, off, 64);
    if (lane==0) csum[j] = f;
  }
  __syncthreads();
  if (tid<64) PSUM[blockIdx.x*64 + tid] = csum[tid];
}

// ---------------- K_msum: fold PSUM -> MEANACC ------------------------------
__global__ void k_msum(const float* __restrict__ PSUM, float* __restrict__ MEANACC){
  int cc = blockIdx.x;           // 128 channels
  int bc = cc>>6, j = cc&63;
  int tid = threadIdx.x;         // 256
  float acc = 0.f;
  for (int bs=tid; bs<512; bs+=256) acc += PSUM[(bs*2+bc)*64 + j];
  #pragma unroll
  for (int off=32; off; off>>=1) acc += __shfl_xor(acc, off, 64);
  __shared__ float red[4];
  if ((tid&63)==0) red[tid>>6] = acc;
  __syncthreads();
  if (tid==0) MEANACC[cc] = red[0]+red[1]+red[2]+red[3];
}

// ---------------- K11: channel attention (mean scale folded in) -------------
__global__ void k_ca(const float* __restrict__ MEANACC, const float* __restrict__ w1, const float* __restrict__ b1,
                     const float* __restrict__ w2, const float* __restrict__ b2, float* __restrict__ SIG){
  __shared__ float y1[8];
  int tid = threadIdx.x;
  if (tid<8){
    float acc = b1[tid];
    for (int c=0;c<128;c++) acc += w1[tid*128+c]*(MEANACC[c]*(1.f/LSEQ));
    y1[tid] = (acc>=0.f)? acc : 0.1f*acc;
  }
  __syncthreads();
  float acc = b2[tid];
  #pragma unroll
  for (int o=0;o<8;o++) acc += w2[tid*8+o]*y1[o];
  SIG[tid] = sigmoidf_(acc);
}

// ---------------- K12: out = x + fused * sigmoid(yc) ------------------------
__global__ void k_final(const float* __restrict__ x, const float* __restrict__ F, const float* __restrict__ SIG,
                        float* __restrict__ out){
  int idx = blockIdx.x*256 + threadIdx.x;
  int cc = idx>>15;
  out[idx] = x[idx] + F[idx]*SIG[cc];
}

extern "C" void kernel_launch(void* const* d_in, const int* in_sizes, int n_in,
                              void* d_out, int out_size, void* d_ws, size_t ws_size,
                              hipStream_t stream){
  (void)in_sizes; (void)n_in; (void)out_size; (void)ws_size;
  const float* x       = (const float*)d_in[0];
  const float* norm_w  = (const float*)d_in[1];
  const float* gate_w  = (const float*)d_in[2];
  const float* gate_b  = (const float*)d_in[3];
  const float* loc_dw_w= (const float*)d_in[28];
  const float* loc_dw_b= (const float*)d_in[29];
  const float* loc_pw_w= (const float*)d_in[30];
  const float* loc_pw_b= (const float*)d_in[31];
  const float* ca_w1   = (const float*)d_in[32];
  const float* ca_b1   = (const float*)d_in[33];
  const float* ca_w2   = (const float*)d_in[34];
  const float* ca_b2   = (const float*)d_in[35];
  const float* alpha   = (const float*)d_in[36];

  float* W     = (float*)d_ws;
  float* XN    = W;                         // 4,194,304
  float* GATES = XN    + 4194304;           //   196,608
  float* GACC  = GATES + 196608;            // 4,194,304
  u16*   ZX    = (u16*)(GACC + 4194304);    // 21,102,592 u16
  u16*   XB    = (u16*)(GACC + 4194304 + 10551296);   // 12,582,912 u16
  float* DT    = GACC + 4194304 + 10551296 + 6291456; // 131,072
  float* CUM   = DT    + 131072;            //   131,072
  float* CDEC  = CUM   + 131072;            //     1,024
  float* STreg = CDEC  + 1024;              // 4,194,304 fl region (ST16 / YH alias)
  float* Y     = STreg + 4194304;           // 8,388,608 fl = YA/YB fp16
  float* LC1   = Y     + 8388608;           // 4,194,304 (HPREV16 alias)
  float* LC2   = LC1   + 4194304;           // 4,194,304
  float* MEAN  = LC2   + 4194304;           //       128
  float* SIG   = MEAN  + 128;               //       128
  float* PSUM  = SIG   + 128;               //    65,536
  u16*   XNT   = (u16*)(PSUM + 65536);      // 4,194,304 u16
  u16*   WinT  = XNT + 4194304;             //    81,920 u16
  u16*   WoT   = WinT + 98304;              //    32,768 u16
  u16*   ST16  = (u16*)STreg;               // 4,194,304 u16
  u16*   YH    = (u16*)STreg;               // alias (ST dead after k_inter)
  u16*   YA    = (u16*)Y;                   // 8,388,608 u16
  u16*   YB    = YA + 8388608;              // 8,388,608 u16
  u16*   HP16  = (u16*)LC1;                 // 4,194,304 u16

  k_xng<<<128,256,0,stream>>>(x, norm_w, gate_w, gate_b, XN, GATES);

  for (int r=0;r<6;r++){
    int m = r>>1;
    const float* Win   = (const float*)d_in[4 + m*8 + 0];
    const float* convw = (const float*)d_in[4 + m*8 + 1];
    const float* convb = (const float*)d_in[4 + m*8 + 2];
    const float* dtb   = (const float*)d_in[4 + m*8 + 3];
    const float* Alog  = (const float*)d_in[4 + m*8 + 4];
    const float* Dp    = (const float*)d_in[4 + m*8 + 5];
    const float* nw2   = (const float*)d_in[4 + m*8 + 6];
    const float* Wout  = (const float*)d_in[4 + m*8 + 7];
    if ((r&1)==0){
      k_permute<<<1024,256,0,stream>>>(XN, XNT, m);
      k_prepw  <<<320,256,0,stream>>>(Win, WinT);
      k_prewo  <<<128,256,0,stream>>>(Wout, WoT);
    }
    k_gin_mfma<<<dim3(5,256),256,0,stream>>>(XNT, WinT, ZX, r&1);
    k_conv    <<<1024,384,0,stream>>>(ZX, convw, convb, XB);
    k_dtcum   <<<256,256,0,stream>>>(XNT, Win, dtb, Alog, DT, CUM, CDEC, r&1);
    k_chunk   <<<1024,256,0,stream>>>(XB, DT, CUM, Dp, YA, ST16);
    k_scan    <<<256,64,0,stream>>>(ST16, HP16, CDEC);
    k_inter   <<<256,256,0,stream>>>(XB, CUM, HP16, YB);
    k_ynorm   <<<8192,256,0,stream>>>(YA, YB, ZX, nw2, YH);
    k_gout_mfma<<<256,256,0,stream>>>(YH, WoT, GATES, GACC, r);
  }

  k_dwconv<<<4096,256,0,stream>>>(XN, loc_dw_w, loc_dw_b, LC1);
  k_pw    <<<256,256,0,stream>>>(LC1, loc_pw_w, loc_pw_b, LC2);
  k_fuse  <<<1024,256,0,stream>>>(GACC, LC2, alpha, LC1, PSUM);
  k_msum  <<<128,256,0,stream>>>(PSUM, MEAN);
  k_ca    <<<1,128,0,stream>>>(MEAN, ca_w1, ca_b1, ca_w2, ca_b2, SIG);
  k_final <<<16384,256,0,stream>>>(x, LC1, SIG, (float*)d_out);
}